// Round 20
// baseline (404.780 us; speedup 1.0000x reference)
//
#include <hip/hip_runtime.h>
#include <math.h>

#define IN_DIM 512
#define DD 256

typedef _Float16 half8_t __attribute__((ext_vector_type(8)));
typedef __attribute__((ext_vector_type(4))) float f32x4_t;

// ---- prep: w2[i] = W[i,:] . a_w[D:2D]; one wave per row, coalesced ----
__global__ __launch_bounds__(256) void prep_w2(const float* __restrict__ W,
                                               const float* __restrict__ a_w,
                                               float* __restrict__ w2) {
  int row = (blockIdx.x * 256 + threadIdx.x) >> 6;  // 0..255
  int lane = threadIdx.x & 63;
  if (row >= DD) return;
  float4 wv = *reinterpret_cast<const float4*>(&W[(size_t)row * DD + lane * 4]);
  float4 av = *reinterpret_cast<const float4*>(&a_w[DD + lane * 4]);
  float s = wv.x * av.x + wv.y * av.y + wv.z * av.z + wv.w * av.w;
#pragma unroll
  for (int d = 32; d; d >>= 1) s += __shfl_xor(s, d, 64);
  if (lane == 0) w2[row] = s;
}

// ---- convert Wm_o to MFMA-fragment-ordered fp16 ----
__global__ void bconv_kernel(const float* __restrict__ Wm, _Float16* __restrict__ Bh) {
  int i = blockIdx.x * 256 + threadIdx.x;  // 0..131071
  int k = i >> 8, col = i & 255;
  int kc16 = k >> 5, kr = k & 31;
  int lane = ((kr >> 3) << 4) | (col & 15);
  int nf = col >> 4;
  int off = (((((kc16 << 4) + nf) << 6) + lane) << 3) + (kr & 7);
  Bh[off] = (_Float16)Wm[i];
}

__device__ __forceinline__ half8_t cvt8(const float4& a, const float4& b) {
  half8_t h;
  h[0] = (_Float16)a.x; h[1] = (_Float16)a.y; h[2] = (_Float16)a.z; h[3] = (_Float16)a.w;
  h[4] = (_Float16)b.x; h[5] = (_Float16)b.y; h[6] = (_Float16)b.z; h[7] = (_Float16)b.w;
  return h;
}

__device__ __forceinline__ void gload16(const void* g, void* l) {
  __builtin_amdgcn_global_load_lds(
      (const __attribute__((address_space(1))) void*)g,
      (__attribute__((address_space(3))) void*)l, 16, 0, 0);
}

// ---- MFMA GEMM, occupancy-first: 16 rows x 128 cols PER WAVE (acc = 32
// VGPR), block = 32 rows x 256 cols, LDS = 2 x 16KB dbuf -> 4 blocks/CU,
// launch_bounds(256,4) = 16 waves/CU. Minimal 2-phase pipeline (stage kc+1,
// MFMA kc, vmcnt(0)+barrier): per-iter drain covered by 3 other blocks.
// Cross-wave LDS reduce in epilogue for row-norm/dot (col halves). ----
__global__ __launch_bounds__(256, 4) void map_gemm_mfma(
    const float* __restrict__ X, const _Float16* __restrict__ Bh,
    const float* __restrict__ bm, const float* __restrict__ w2,
    float* __restrict__ Yn, _Float16* __restrict__ Y16,
    float* __restrict__ wnorm, int M) {
  __shared__ _Float16 Bs[2][8192];  // 2 x 16KB
  const int t = threadIdx.x;
  const int w = t >> 6;
  const int l = t & 63;
  const int c = l & 15;
  const int g = l >> 4;
  const int rh = w & 1;   // row half (0: rows 0-15, 1: rows 16-31)
  const int ch = w >> 1;  // col half (0: cols 0-127, 1: cols 128-255)
  const int row0 = blockIdx.x * 32 + rh * 16;

  int arow = row0 + c;
  if (arow >= M) arow = M - 1;  // clamp; tail rows computed, never stored
  const float* xrow = X + (size_t)arow * IN_DIM;

  f32x4_t acc[8];
#pragma unroll
  for (int n = 0; n < 8; ++n) acc[n] = (f32x4_t){0.f, 0.f, 0.f, 0.f};

  const char* bbytes = reinterpret_cast<const char*>(Bh);
  const int soff = (w << 12) + (l << 4);  // this wave stages bytes [w*4K, w*4K+4K)

  float4 a0[2], a1[2];  // chunk-parity A register sets (1-ahead)

  // ---- prologue: stage chunk 0 -> buf0; load A chunk 0 ----
#pragma unroll
  for (int j = 0; j < 4; ++j)
    gload16(bbytes + soff + j * 1024, (char*)&Bs[0][0] + soff + j * 1024);
  a0[0] = *reinterpret_cast<const float4*>(xrow + g * 8);
  a0[1] = *reinterpret_cast<const float4*>(xrow + g * 8 + 4);
  asm volatile("s_waitcnt vmcnt(0)" ::: "memory");
  __builtin_amdgcn_s_barrier();
  asm volatile("" ::: "memory");
  __builtin_amdgcn_sched_barrier(0);

#pragma unroll
  for (int kc = 0; kc < 16; ++kc) {
    const int cur = kc & 1;
    // A frag of chunk kc (set cur) -- read BEFORE anything overwrites sets
    half8_t ah = (cur == 0) ? cvt8(a0[0], a0[1]) : cvt8(a1[0], a1[1]);

    // issue chunk kc+1: B -> buf[cur^1] (its chunk-(kc-1) readers closed at
    // the barrier we just passed), A -> set cur^1 (dead since chunk kc-1)
    if (kc < 15) {
      const char* gb = bbytes + (kc + 1) * 16384;
      char* lb = (char*)&Bs[cur ^ 1][0];
#pragma unroll
      for (int j = 0; j < 4; ++j)
        gload16(gb + soff + j * 1024, lb + soff + j * 1024);
      const float* xp = xrow + (kc + 1) * 32 + g * 8;
      if (cur == 0) {
        a1[0] = *reinterpret_cast<const float4*>(xp);
        a1[1] = *reinterpret_cast<const float4*>(xp + 4);
      } else {
        a0[0] = *reinterpret_cast<const float4*>(xp);
        a0[1] = *reinterpret_cast<const float4*>(xp + 4);
      }
    }

    // compute chunk kc: 8 col-frags of this wave's col half
    const _Float16* bp = &Bs[cur][0];
    __builtin_amdgcn_s_setprio(1);
#pragma unroll
    for (int n = 0; n < 8; ++n) {
      half8_t bh = *reinterpret_cast<const half8_t*>(&bp[((ch << 3) + n) * 512 + l * 8]);
      acc[n] = __builtin_amdgcn_mfma_f32_16x16x32_f16(ah, bh, acc[n], 0, 0, 0);
    }
    __builtin_amdgcn_s_setprio(0);

    // close chunk kc; chunk kc+1 must be fully staged before next iter reads
    if (kc < 15) {
      asm volatile("s_waitcnt vmcnt(0)" ::: "memory");
      __builtin_amdgcn_s_barrier();
      asm volatile("" ::: "memory");
      __builtin_amdgcn_sched_barrier(0);
    }
  }

  // ---- epilogue: bias+relu, partial row-dot/norm over this col half,
  // width-16 butterfly, cross-wave combine via LDS, normalized stores ----
  float ssq[4] = {0.f, 0.f, 0.f, 0.f}, dtq[4] = {0.f, 0.f, 0.f, 0.f};
#pragma unroll
  for (int n = 0; n < 8; ++n) {
    int col = (ch << 7) + (n << 4) + c;
    float bvn = bm[col];
    float wvn = w2[col];
#pragma unroll
    for (int q = 0; q < 4; ++q) {
      float v = acc[n][q] + bvn;
      v = v > 0.f ? v : 0.f;
      acc[n][q] = v;
      ssq[q] = fmaf(v, v, ssq[q]);
      dtq[q] = fmaf(v, wvn, dtq[q]);
    }
  }
#pragma unroll
  for (int q = 0; q < 4; ++q) {
#pragma unroll
    for (int d = 1; d < 16; d <<= 1) {
      ssq[q] += __shfl_xor(ssq[q], d, 16);
      dtq[q] += __shfl_xor(dtq[q], d, 16);
    }
  }
  // cross-wave combine: red[rh][ch][row16][2]
  float* red = reinterpret_cast<float*>(&Bs[0][0]);
  __syncthreads();  // all waves done reading Bs[1] (last MFMA)
  if (c == 0) {
#pragma unroll
    for (int q = 0; q < 4; ++q) {
      int rr = (g << 2) + q;
      red[((((rh << 1) + ch) << 4) + rr) * 2 + 0] = ssq[q];
      red[((((rh << 1) + ch) << 4) + rr) * 2 + 1] = dtq[q];
    }
  }
  __syncthreads();
  float inv[4];
#pragma unroll
  for (int q = 0; q < 4; ++q) {
    int rr = (g << 2) + q;
    float ss = red[(((rh << 1) + 0) << 4) * 2 + rr * 2 + 0] +
               red[(((rh << 1) + 1) << 4) * 2 + rr * 2 + 0];
    float nr = sqrtf(ss);
    inv[q] = 1.f / fmaxf(nr, 1e-12f);
    int r = row0 + rr;
    if (c == 0 && ch == 0 && r < M) {
      float dt = red[(((rh << 1) + 0) << 4) * 2 + rr * 2 + 1] +
                 red[(((rh << 1) + 1) << 4) * 2 + rr * 2 + 1];
      wnorm[r] = expf(dt) * nr;
    }
  }
#pragma unroll
  for (int q = 0; q < 4; ++q) {
    int r = row0 + (g << 2) + q;
    if (r < M) {
#pragma unroll
      for (int n = 0; n < 8; ++n) {
        float v = acc[n][q] * inv[q];
        int col = (ch << 7) + (n << 4) + c;
        Yn[(size_t)r * DD + col] = v;
        Y16[(size_t)r * DD + col] = (_Float16)v;
      }
    }
  }
}

// ---- CSR build ----
__global__ void hist_kernel(const int* __restrict__ src, int* __restrict__ deg, int E) {
  int i = blockIdx.x * blockDim.x + threadIdx.x;
  if (i < E) atomicAdd(&deg[src[i]], 1);
}

__global__ __launch_bounds__(256) void scan_part(const int* __restrict__ deg,
                                                 int* __restrict__ bsum, int NP) {
  __shared__ int s[256];
  int t = threadIdx.x, b = blockIdx.x;
  int i0 = (b * 256 + t) * 2;
  int v0 = (i0 < NP) ? deg[i0] : 0;
  int v1 = (i0 + 1 < NP) ? deg[i0 + 1] : 0;
  s[t] = v0 + v1;
  __syncthreads();
  for (int off = 128; off; off >>= 1) {
    if (t < off) s[t] += s[t + off];
    __syncthreads();
  }
  if (t == 0) bsum[b] = s[0];
}

__global__ __launch_bounds__(256) void scan_fin2(const int* __restrict__ deg,
                                                 const int* __restrict__ bsum,
                                                 int* __restrict__ rowptr,
                                                 int* __restrict__ cursor, int NP) {
  __shared__ int s[256];
  __shared__ int base_s;
  int t = threadIdx.x, b = blockIdx.x;
  int v = (t < b) ? bsum[t] : 0;
  s[t] = v;
  __syncthreads();
  for (int off = 128; off; off >>= 1) {
    if (t < off) s[t] += s[t + off];
    __syncthreads();
  }
  if (t == 0) base_s = s[0];
  __syncthreads();
  int base0 = base_s;
  __syncthreads();
  int i0 = (b * 256 + t) * 2;
  int v0 = (i0 < NP) ? deg[i0] : 0;
  int v1 = (i0 + 1 < NP) ? deg[i0 + 1] : 0;
  int local = v0 + v1;
  s[t] = local;
  __syncthreads();
  for (int off = 1; off < 256; off <<= 1) {
    int u = (t >= off) ? s[t - off] : 0;
    __syncthreads();
    s[t] += u;
    __syncthreads();
  }
  int myb = base0 + s[t] - local;
  if (i0 < NP) { rowptr[i0] = myb; cursor[i0] = myb; }
  if (i0 + 1 < NP) { rowptr[i0 + 1] = myb + v0; cursor[i0 + 1] = myb + v0; }
  if (b == gridDim.x - 1 && t == 255) rowptr[NP] = base0 + s[255];
}

__global__ void fill_kernel(const int* __restrict__ src, const int* __restrict__ dst,
                            int* __restrict__ cursor, int* __restrict__ ebuf, int E) {
  int i = blockIdx.x * blockDim.x + threadIdx.x;
  if (i < E) {
    int pos = atomicAdd(&cursor[src[i]], 1);
    ebuf[pos] = dst[i];
  }
}

// ---- per-segment: out = l2norm(sum wnorm[d] * hon16[d]); 16 lanes/node ----
__global__ __launch_bounds__(256) void agg_kernel(const int* __restrict__ rowptr,
                                                  const int* __restrict__ ebuf,
                                                  const float* __restrict__ wnorm,
                                                  const _Float16* __restrict__ hon16,
                                                  float* __restrict__ agg, int NP) {
  long gid = (long)blockIdx.x * blockDim.x + threadIdx.x;
  int wid = (int)(gid >> 6);
  int lane = threadIdx.x & 63;
  int sg = lane >> 4;
  int li = lane & 15;
  int p = wid * 4 + sg;
  if (p >= NP) return;
  int beg = rowptr[p], end = rowptr[p + 1];
  float acc[16];
#pragma unroll
  for (int k = 0; k < 16; ++k) acc[k] = 0.f;
  if (beg < end) {
    int d = ebuf[beg];
    float w = wnorm[d];
    const half8_t* rp = reinterpret_cast<const half8_t*>(&hon16[(size_t)d * DD + li * 16]);
    half8_t v0 = rp[0], v1 = rp[1];
    for (int j = beg + 1; j <= end; ++j) {
      half8_t n0, n1;
      float wn_ = 0.f;
      bool have = (j < end);
      if (have) {
        int dn = ebuf[j];
        wn_ = wnorm[dn];
        const half8_t* np_ = reinterpret_cast<const half8_t*>(&hon16[(size_t)dn * DD + li * 16]);
        n0 = np_[0]; n1 = np_[1];
      }
#pragma unroll
      for (int k = 0; k < 8; ++k) {
        acc[k] = fmaf(w, (float)v0[k], acc[k]);
        acc[8 + k] = fmaf(w, (float)v1[k], acc[8 + k]);
      }
      if (have) { w = wn_; v0 = n0; v1 = n1; }
    }
  }
  float ss = 0.f;
#pragma unroll
  for (int k = 0; k < 16; ++k) ss = fmaf(acc[k], acc[k], ss);
#pragma unroll
  for (int d2 = 8; d2 > 0; d2 >>= 1) ss += __shfl_xor(ss, d2, 16);
  float inv = 1.0f / fmaxf(sqrtf(ss), 1e-12f);
  float* op = &agg[(size_t)p * DD + li * 16];
#pragma unroll
  for (int k = 0; k < 4; ++k) {
    float4 o = {acc[k * 4] * inv, acc[k * 4 + 1] * inv,
                acc[k * 4 + 2] * inv, acc[k * 4 + 3] * inv};
    *reinterpret_cast<float4*>(op + k * 4) = o;
  }
}

extern "C" void kernel_launch(void* const* d_in, const int* in_sizes, int n_in,
                              void* d_out, int out_size, void* d_ws, size_t ws_size,
                              hipStream_t stream) {
  const float* feat_other = (const float*)d_in[1];
  const int* src = (const int*)d_in[2];
  const int* dst = (const int*)d_in[3];
  const float* Wm_o = (const float*)d_in[6];
  const float* bm_o = (const float*)d_in[7];
  const float* W = (const float*)d_in[8];
  const float* a_w = (const float*)d_in[10];

  const int NP = in_sizes[0] / IN_DIM;
  const int NO = in_sizes[1] / IN_DIM;
  const int E = in_sizes[2];

  float* out = (float*)d_out;
  float* agg_out = out;                      // [NP, DD]
  float* ho_out = out + (size_t)NP * DD;     // [NO, DD]

  float* ws = (float*)d_ws;
  float* wnorm = ws;                          // NO
  float* w2 = wnorm + NO;                     // 256
  int* deg = (int*)(w2 + 256);                // NP (memset 0)
  int* rowptr = deg + NP;                     // NP+1
  int* cursor = rowptr + NP + 1;              // NP
  int* bsum = cursor + NP;                    // 256
  int* ebuf = bsum + 256;                     // E
  size_t foff = (size_t)NO + 256 + NP + (NP + 1) + NP + 256 + E;
  foff = (foff + 3) & ~(size_t)3;             // 16B align
  _Float16* Bh = (_Float16*)(ws + foff);      // 131072 halves
  _Float16* Y16 = Bh + (size_t)IN_DIM * DD;   // NO * DD halves

  hipMemsetAsync(deg, 0, (size_t)NP * sizeof(int), stream);

  prep_w2<<<64, 256, 0, stream>>>(W, a_w, w2);
  bconv_kernel<<<(IN_DIM * DD) / 256, 256, 0, stream>>>(Wm_o, Bh);

  map_gemm_mfma<<<(NO + 31) / 32, 256, 0, stream>>>(
      feat_other, Bh, bm_o, w2, ho_out, Y16, wnorm, NO);

  hist_kernel<<<(E + 255) / 256, 256, 0, stream>>>(src, deg, E);
  scan_part<<<256, 256, 0, stream>>>(deg, bsum, NP);
  scan_fin2<<<256, 256, 0, stream>>>(deg, bsum, rowptr, cursor, NP);
  fill_kernel<<<(E + 255) / 256, 256, 0, stream>>>(src, dst, cursor, ebuf, E);

  agg_kernel<<<(NP + 15) / 16, 256, 0, stream>>>(
      rowptr, ebuf, wnorm, Y16, agg_out, NP);
}

// Round 21
// 334.069 us; speedup vs baseline: 1.2117x; 1.2117x over previous
//
#include <hip/hip_runtime.h>
#include <math.h>

#define IN_DIM 512
#define DD 256

typedef _Float16 half8_t __attribute__((ext_vector_type(8)));
typedef __attribute__((ext_vector_type(4))) float f32x4_t;

// ---- fused: blocks 0..511 convert Wm_o to MFMA-fragment-ordered fp16;
//      blocks 512..575 compute w2[i] = W[i,:] . a_w[D:2D] (wave per row) ----
__global__ __launch_bounds__(256) void bconv_prep(
    const float* __restrict__ Wm, _Float16* __restrict__ Bh,
    const float* __restrict__ W, const float* __restrict__ a_w,
    float* __restrict__ w2) {
  if (blockIdx.x < 512) {
    int i = blockIdx.x * 256 + threadIdx.x;  // 0..131071
    int k = i >> 8, col = i & 255;
    int kc16 = k >> 5, kr = k & 31;
    int lane = ((kr >> 3) << 4) | (col & 15);
    int nf = col >> 4;
    int off = (((((kc16 << 4) + nf) << 6) + lane) << 3) + (kr & 7);
    Bh[off] = (_Float16)Wm[i];
  } else {
    int row = ((blockIdx.x - 512) * 256 + threadIdx.x) >> 6;  // 0..255
    int lane = threadIdx.x & 63;
    if (row >= DD) return;
    float4 wv = *reinterpret_cast<const float4*>(&W[(size_t)row * DD + lane * 4]);
    float4 av = *reinterpret_cast<const float4*>(&a_w[DD + lane * 4]);
    float s = wv.x * av.x + wv.y * av.y + wv.z * av.z + wv.w * av.w;
#pragma unroll
    for (int d = 32; d; d >>= 1) s += __shfl_xor(s, d, 64);
    if (lane == 0) w2[row] = s;
  }
}

__device__ __forceinline__ half8_t cvt8(const float4& a, const float4& b) {
  half8_t h;
  h[0] = (_Float16)a.x; h[1] = (_Float16)a.y; h[2] = (_Float16)a.z; h[3] = (_Float16)a.w;
  h[4] = (_Float16)b.x; h[5] = (_Float16)b.y; h[6] = (_Float16)b.z; h[7] = (_Float16)b.w;
  return h;
}

__device__ __forceinline__ void gload16(const void* g, void* l) {
  __builtin_amdgcn_global_load_lds(
      (const __attribute__((address_space(1))) void*)g,
      (__attribute__((address_space(3))) void*)l, 16, 0, 0);
}

// ---- MFMA GEMM (R19-best, reverted): 32 rows/wave, 128-row blocks; B via
// global_load_lds into QUAD-buffered LDS, 3-step-ahead counted vmcnt(16);
// A 3-deep register sets; full fences; in-register epilogue. ----
__global__ __launch_bounds__(256, 2) void map_gemm_mfma(
    const float* __restrict__ X, const _Float16* __restrict__ Bh,
    const float* __restrict__ bm, const float* __restrict__ w2,
    float* __restrict__ Yn, _Float16* __restrict__ Y16,
    float* __restrict__ wnorm, int M) {
  __shared__ _Float16 Bs[4][8192];  // 4 x 16KB
  const int t = threadIdx.x;
  const int wv = t >> 6;
  const int l = t & 63;
  const int c = l & 15;
  const int g = l >> 4;
  const int row0 = blockIdx.x * 128 + wv * 32;  // wave's 32-row strip

  int arow0 = row0 + c;       if (arow0 >= M) arow0 = M - 1;
  int arow1 = row0 + 16 + c;  if (arow1 >= M) arow1 = M - 1;
  const float* xrow0 = X + (size_t)arow0 * IN_DIM;
  const float* xrow1 = X + (size_t)arow1 * IN_DIM;

  f32x4_t acc[2][16];
#pragma unroll
  for (int rf = 0; rf < 2; ++rf)
#pragma unroll
    for (int n = 0; n < 16; ++n) acc[rf][n] = (f32x4_t){0.f, 0.f, 0.f, 0.f};

  const char* bbytes = reinterpret_cast<const char*>(Bh);
  const int lane16 = l * 16;

  float4 A0[2][2], A1[2][2], A2[2][2];

  // ---- prologue: batches 0,1,2 (each: 4 gload_lds + 4 float4), fence-pinned ----
#pragma unroll
  for (int j = 0; j < 4; ++j)
    gload16(bbytes + ((wv << 2) + j) * 1024 + lane16,
            (char*)&Bs[0][0] + ((wv << 2) + j) * 1024);
  A0[0][0] = *reinterpret_cast<const float4*>(xrow0 + g * 8);
  A0[0][1] = *reinterpret_cast<const float4*>(xrow0 + g * 8 + 4);
  A0[1][0] = *reinterpret_cast<const float4*>(xrow1 + g * 8);
  A0[1][1] = *reinterpret_cast<const float4*>(xrow1 + g * 8 + 4);
  asm volatile("" ::: "memory");
#pragma unroll
  for (int j = 0; j < 4; ++j)
    gload16(bbytes + 16384 + ((wv << 2) + j) * 1024 + lane16,
            (char*)&Bs[1][0] + ((wv << 2) + j) * 1024);
  A1[0][0] = *reinterpret_cast<const float4*>(xrow0 + 32 + g * 8);
  A1[0][1] = *reinterpret_cast<const float4*>(xrow0 + 32 + g * 8 + 4);
  A1[1][0] = *reinterpret_cast<const float4*>(xrow1 + 32 + g * 8);
  A1[1][1] = *reinterpret_cast<const float4*>(xrow1 + 32 + g * 8 + 4);
  asm volatile("" ::: "memory");
#pragma unroll
  for (int j = 0; j < 4; ++j)
    gload16(bbytes + 32768 + ((wv << 2) + j) * 1024 + lane16,
            (char*)&Bs[2][0] + ((wv << 2) + j) * 1024);
  A2[0][0] = *reinterpret_cast<const float4*>(xrow0 + 64 + g * 8);
  A2[0][1] = *reinterpret_cast<const float4*>(xrow0 + 64 + g * 8 + 4);
  A2[1][0] = *reinterpret_cast<const float4*>(xrow1 + 64 + g * 8);
  A2[1][1] = *reinterpret_cast<const float4*>(xrow1 + 64 + g * 8 + 4);

#pragma unroll
  for (int kc = 0; kc < 16; ++kc) {
    if (kc <= 13) {
      asm volatile("s_waitcnt vmcnt(16)" ::: "memory");
    } else if (kc == 14) {
      asm volatile("s_waitcnt vmcnt(8)" ::: "memory");
    } else {
      asm volatile("s_waitcnt vmcnt(0)" ::: "memory");
    }
    __builtin_amdgcn_s_barrier();
    asm volatile("" ::: "memory");           // IR fence
    __builtin_amdgcn_sched_barrier(0);       // MIR fence

    half8_t ah0, ah1;
    if (kc % 3 == 0)      { ah0 = cvt8(A0[0][0], A0[0][1]); ah1 = cvt8(A0[1][0], A0[1][1]); }
    else if (kc % 3 == 1) { ah0 = cvt8(A1[0][0], A1[0][1]); ah1 = cvt8(A1[1][0], A1[1][1]); }
    else                  { ah0 = cvt8(A2[0][0], A2[0][1]); ah1 = cvt8(A2[1][0], A2[1][1]); }

    if (kc <= 12) {
      const char* gb = bbytes + (kc + 3) * 16384;
      char* lb = (char*)&Bs[(kc + 3) % 4][0];
#pragma unroll
      for (int j = 0; j < 4; ++j)
        gload16(gb + ((wv << 2) + j) * 1024 + lane16, lb + ((wv << 2) + j) * 1024);
      const float* xp0 = xrow0 + (kc + 3) * 32 + g * 8;
      const float* xp1 = xrow1 + (kc + 3) * 32 + g * 8;
      if (kc % 3 == 0) {
        A0[0][0] = *reinterpret_cast<const float4*>(xp0);
        A0[0][1] = *reinterpret_cast<const float4*>(xp0 + 4);
        A0[1][0] = *reinterpret_cast<const float4*>(xp1);
        A0[1][1] = *reinterpret_cast<const float4*>(xp1 + 4);
      } else if (kc % 3 == 1) {
        A1[0][0] = *reinterpret_cast<const float4*>(xp0);
        A1[0][1] = *reinterpret_cast<const float4*>(xp0 + 4);
        A1[1][0] = *reinterpret_cast<const float4*>(xp1);
        A1[1][1] = *reinterpret_cast<const float4*>(xp1 + 4);
      } else {
        A2[0][0] = *reinterpret_cast<const float4*>(xp0);
        A2[0][1] = *reinterpret_cast<const float4*>(xp0 + 4);
        A2[1][0] = *reinterpret_cast<const float4*>(xp1);
        A2[1][1] = *reinterpret_cast<const float4*>(xp1 + 4);
      }
    }

    const _Float16* bp = &Bs[kc % 4][0];
    __builtin_amdgcn_s_setprio(1);
#pragma unroll
    for (int n = 0; n < 16; ++n) {
      half8_t bh = *reinterpret_cast<const half8_t*>(&bp[n * 512 + l * 8]);
      acc[0][n] = __builtin_amdgcn_mfma_f32_16x16x32_f16(ah0, bh, acc[0][n], 0, 0, 0);
      acc[1][n] = __builtin_amdgcn_mfma_f32_16x16x32_f16(ah1, bh, acc[1][n], 0, 0, 0);
    }
    __builtin_amdgcn_s_setprio(0);
  }

#pragma unroll
  for (int rf = 0; rf < 2; ++rf) {
    float ssq[4] = {0.f, 0.f, 0.f, 0.f}, dtq[4] = {0.f, 0.f, 0.f, 0.f};
#pragma unroll
    for (int n = 0; n < 16; ++n) {
      float bvn = bm[n * 16 + c];
      float wvn = w2[n * 16 + c];
#pragma unroll
      for (int q = 0; q < 4; ++q) {
        float v = acc[rf][n][q] + bvn;
        v = v > 0.f ? v : 0.f;
        acc[rf][n][q] = v;
        ssq[q] = fmaf(v, v, ssq[q]);
        dtq[q] = fmaf(v, wvn, dtq[q]);
      }
    }
#pragma unroll
    for (int q = 0; q < 4; ++q) {
#pragma unroll
      for (int d = 1; d < 16; d <<= 1) {
        ssq[q] += __shfl_xor(ssq[q], d, 16);
        dtq[q] += __shfl_xor(dtq[q], d, 16);
      }
    }
    float inv[4];
#pragma unroll
    for (int q = 0; q < 4; ++q) {
      float nr = sqrtf(ssq[q]);
      inv[q] = 1.f / fmaxf(nr, 1e-12f);
      int r = row0 + rf * 16 + g * 4 + q;
      if (c == 0 && r < M) wnorm[r] = expf(dtq[q]) * nr;
    }
#pragma unroll
    for (int q = 0; q < 4; ++q) {
      int r = row0 + rf * 16 + g * 4 + q;
      if (r < M) {
#pragma unroll
        for (int n = 0; n < 16; ++n) {
          float v = acc[rf][n][q] * inv[q];
          Yn[(size_t)r * DD + n * 16 + c] = v;
          Y16[(size_t)r * DD + n * 16 + c] = (_Float16)v;
        }
      }
    }
  }
}

// ---- CSR build ----
__global__ void hist_kernel(const int* __restrict__ src, int* __restrict__ deg, int E) {
  int i = blockIdx.x * blockDim.x + threadIdx.x;
  if (i < E) atomicAdd(&deg[src[i]], 1);
}

__global__ __launch_bounds__(256) void scan_part(const int* __restrict__ deg,
                                                 int* __restrict__ bsum, int NP) {
  __shared__ int s[256];
  int t = threadIdx.x, b = blockIdx.x;
  int i0 = (b * 256 + t) * 2;
  int v0 = (i0 < NP) ? deg[i0] : 0;
  int v1 = (i0 + 1 < NP) ? deg[i0 + 1] : 0;
  s[t] = v0 + v1;
  __syncthreads();
  for (int off = 128; off; off >>= 1) {
    if (t < off) s[t] += s[t + off];
    __syncthreads();
  }
  if (t == 0) bsum[b] = s[0];
}

__global__ __launch_bounds__(256) void scan_fin2(const int* __restrict__ deg,
                                                 const int* __restrict__ bsum,
                                                 int* __restrict__ rowptr,
                                                 int* __restrict__ cursor, int NP) {
  __shared__ int s[256];
  __shared__ int base_s;
  int t = threadIdx.x, b = blockIdx.x;
  int v = (t < b) ? bsum[t] : 0;
  s[t] = v;
  __syncthreads();
  for (int off = 128; off; off >>= 1) {
    if (t < off) s[t] += s[t + off];
    __syncthreads();
  }
  if (t == 0) base_s = s[0];
  __syncthreads();
  int base0 = base_s;
  __syncthreads();
  int i0 = (b * 256 + t) * 2;
  int v0 = (i0 < NP) ? deg[i0] : 0;
  int v1 = (i0 + 1 < NP) ? deg[i0 + 1] : 0;
  int local = v0 + v1;
  s[t] = local;
  __syncthreads();
  for (int off = 1; off < 256; off <<= 1) {
    int u = (t >= off) ? s[t - off] : 0;
    __syncthreads();
    s[t] += u;
    __syncthreads();
  }
  int myb = base0 + s[t] - local;
  if (i0 < NP) { rowptr[i0] = myb; cursor[i0] = myb; }
  if (i0 + 1 < NP) { rowptr[i0 + 1] = myb + v0; cursor[i0 + 1] = myb + v0; }
  if (b == gridDim.x - 1 && t == 255) rowptr[NP] = base0 + s[255];
}

// fill with packed payload: ebuf2[pos] = {dst, wnorm[dst] bits} -- moves the
// wnorm gather off agg's serial chain into this fully-parallel pass
__global__ void fill_kernel2(const int* __restrict__ src, const int* __restrict__ dst,
                             const float* __restrict__ wnorm,
                             int* __restrict__ cursor, int2* __restrict__ ebuf2, int E) {
  int i = blockIdx.x * blockDim.x + threadIdx.x;
  if (i < E) {
    int d = dst[i];
    int pos = atomicAdd(&cursor[src[i]], 1);
    ebuf2[pos] = make_int2(d, __float_as_int(wnorm[d]));
  }
}

// ---- per-segment: out = l2norm(sum wnorm[d] * hon16[d]); 16 lanes/node,
// packed int2 edges (one dependent hop less per edge) ----
__global__ __launch_bounds__(256) void agg_kernel(const int* __restrict__ rowptr,
                                                  const int2* __restrict__ ebuf2,
                                                  const _Float16* __restrict__ hon16,
                                                  float* __restrict__ agg, int NP) {
  long gid = (long)blockIdx.x * blockDim.x + threadIdx.x;
  int wid = (int)(gid >> 6);
  int lane = threadIdx.x & 63;
  int sg = lane >> 4;
  int li = lane & 15;
  int p = wid * 4 + sg;
  if (p >= NP) return;
  int beg = rowptr[p], end = rowptr[p + 1];
  float acc[16];
#pragma unroll
  for (int k = 0; k < 16; ++k) acc[k] = 0.f;
  if (beg < end) {
    int2 e0 = ebuf2[beg];
    float w = __int_as_float(e0.y);
    const half8_t* rp = reinterpret_cast<const half8_t*>(&hon16[(size_t)e0.x * DD + li * 16]);
    half8_t v0 = rp[0], v1 = rp[1];
    for (int j = beg + 1; j <= end; ++j) {
      half8_t n0, n1;
      float wn_ = 0.f;
      bool have = (j < end);
      if (have) {
        int2 en = ebuf2[j];
        wn_ = __int_as_float(en.y);
        const half8_t* np_ = reinterpret_cast<const half8_t*>(&hon16[(size_t)en.x * DD + li * 16]);
        n0 = np_[0]; n1 = np_[1];
      }
#pragma unroll
      for (int k = 0; k < 8; ++k) {
        acc[k] = fmaf(w, (float)v0[k], acc[k]);
        acc[8 + k] = fmaf(w, (float)v1[k], acc[8 + k]);
      }
      if (have) { w = wn_; v0 = n0; v1 = n1; }
    }
  }
  float ss = 0.f;
#pragma unroll
  for (int k = 0; k < 16; ++k) ss = fmaf(acc[k], acc[k], ss);
#pragma unroll
  for (int d2 = 8; d2 > 0; d2 >>= 1) ss += __shfl_xor(ss, d2, 16);
  float inv = 1.0f / fmaxf(sqrtf(ss), 1e-12f);
  float* op = &agg[(size_t)p * DD + li * 16];
#pragma unroll
  for (int k = 0; k < 4; ++k) {
    float4 o = {acc[k * 4] * inv, acc[k * 4 + 1] * inv,
                acc[k * 4 + 2] * inv, acc[k * 4 + 3] * inv};
    *reinterpret_cast<float4*>(op + k * 4) = o;
  }
}

extern "C" void kernel_launch(void* const* d_in, const int* in_sizes, int n_in,
                              void* d_out, int out_size, void* d_ws, size_t ws_size,
                              hipStream_t stream) {
  const float* feat_other = (const float*)d_in[1];
  const int* src = (const int*)d_in[2];
  const int* dst = (const int*)d_in[3];
  const float* Wm_o = (const float*)d_in[6];
  const float* bm_o = (const float*)d_in[7];
  const float* W = (const float*)d_in[8];
  const float* a_w = (const float*)d_in[10];

  const int NP = in_sizes[0] / IN_DIM;
  const int NO = in_sizes[1] / IN_DIM;
  const int E = in_sizes[2];

  float* out = (float*)d_out;
  float* agg_out = out;                      // [NP, DD]
  float* ho_out = out + (size_t)NP * DD;     // [NO, DD]

  float* ws = (float*)d_ws;
  float* wnorm = ws;                          // NO
  float* w2 = wnorm + NO;                     // 256
  int* deg = (int*)(w2 + 256);                // NP (memset 0)
  int* rowptr = deg + NP;                     // NP+1
  int* cursor = rowptr + NP + 1;              // NP
  int* bsum = cursor + NP;                    // 256
  int* ebuf_raw = bsum + 256;                 // 2E ints (int2 storage)
  size_t foff = (size_t)NO + 256 + NP + (NP + 1) + NP + 256 + 2 * (size_t)E;
  foff = (foff + 3) & ~(size_t)3;             // 16B align
  _Float16* Bh = (_Float16*)(ws + foff);      // 131072 halves
  _Float16* Y16 = Bh + (size_t)IN_DIM * DD;   // NO * DD halves
  int2* ebuf2 = (int2*)ebuf_raw;

  hipMemsetAsync(deg, 0, (size_t)NP * sizeof(int), stream);

  bconv_prep<<<576, 256, 0, stream>>>(Wm_o, Bh, W, a_w, w2);

  map_gemm_mfma<<<(NO + 127) / 128, 256, 0, stream>>>(
      feat_other, Bh, bm_o, w2, ho_out, Y16, wnorm, NO);

  hist_kernel<<<(E + 255) / 256, 256, 0, stream>>>(src, deg, E);
  scan_part<<<256, 256, 0, stream>>>(deg, bsum, NP);
  scan_fin2<<<256, 256, 0, stream>>>(deg, bsum, rowptr, cursor, NP);
  fill_kernel2<<<(E + 255) / 256, 256, 0, stream>>>(src, dst, wnorm, cursor, ebuf2, E);

  agg_kernel<<<(NP + 15) / 16, 256, 0, stream>>>(
      rowptr, ebuf2, Y16, agg_out, NP);
}

// Round 22
// 331.905 us; speedup vs baseline: 1.2196x; 1.0065x over previous
//
#include <hip/hip_runtime.h>
#include <math.h>

#define IN_DIM 512
#define DD 256

typedef _Float16 half8_t __attribute__((ext_vector_type(8)));
typedef __attribute__((ext_vector_type(4))) float f32x4_t;

// ---- prep: w2[i] = W[i,:] . a_w[D:2D]; one wave per row, coalesced ----
__global__ __launch_bounds__(256) void prep_w2(const float* __restrict__ W,
                                               const float* __restrict__ a_w,
                                               float* __restrict__ w2) {
  int row = (blockIdx.x * 256 + threadIdx.x) >> 6;  // 0..255
  int lane = threadIdx.x & 63;
  if (row >= DD) return;
  float4 wv = *reinterpret_cast<const float4*>(&W[(size_t)row * DD + lane * 4]);
  float4 av = *reinterpret_cast<const float4*>(&a_w[DD + lane * 4]);
  float s = wv.x * av.x + wv.y * av.y + wv.z * av.z + wv.w * av.w;
#pragma unroll
  for (int d = 32; d; d >>= 1) s += __shfl_xor(s, d, 64);
  if (lane == 0) w2[row] = s;
}

// ---- convert Wm_o to MFMA-fragment-ordered fp16 ----
__global__ void bconv_kernel(const float* __restrict__ Wm, _Float16* __restrict__ Bh) {
  int i = blockIdx.x * 256 + threadIdx.x;  // 0..131071
  int k = i >> 8, col = i & 255;
  int kc16 = k >> 5, kr = k & 31;
  int lane = ((kr >> 3) << 4) | (col & 15);
  int nf = col >> 4;
  int off = (((((kc16 << 4) + nf) << 6) + lane) << 3) + (kr & 7);
  Bh[off] = (_Float16)Wm[i];
}

__device__ __forceinline__ half8_t cvt8(const float4& a, const float4& b) {
  half8_t h;
  h[0] = (_Float16)a.x; h[1] = (_Float16)a.y; h[2] = (_Float16)a.z; h[3] = (_Float16)a.w;
  h[4] = (_Float16)b.x; h[5] = (_Float16)b.y; h[6] = (_Float16)b.z; h[7] = (_Float16)b.w;
  return h;
}

__device__ __forceinline__ void gload16(const void* g, void* l) {
  __builtin_amdgcn_global_load_lds(
      (const __attribute__((address_space(1))) void*)g,
      (__attribute__((address_space(3))) void*)l, 16, 0, 0);
}

// ---- MFMA GEMM (best-known, R19): 32 rows/wave, 128-row blocks; B via
// global_load_lds into QUAD-buffered LDS with 3-step-ahead prefetch
// (counted vmcnt(16) steady state); A 3-deep register sets; full fences. ----
__global__ __launch_bounds__(256, 2) void map_gemm_mfma(
    const float* __restrict__ X, const _Float16* __restrict__ Bh,
    const float* __restrict__ bm, const float* __restrict__ w2,
    float* __restrict__ Yn, _Float16* __restrict__ Y16,
    float* __restrict__ wnorm, int M) {
  __shared__ _Float16 Bs[4][8192];  // 4 x 16KB
  const int t = threadIdx.x;
  const int wv = t >> 6;
  const int l = t & 63;
  const int c = l & 15;
  const int g = l >> 4;
  const int row0 = blockIdx.x * 128 + wv * 32;  // wave's 32-row strip

  int arow0 = row0 + c;       if (arow0 >= M) arow0 = M - 1;
  int arow1 = row0 + 16 + c;  if (arow1 >= M) arow1 = M - 1;
  const float* xrow0 = X + (size_t)arow0 * IN_DIM;
  const float* xrow1 = X + (size_t)arow1 * IN_DIM;

  f32x4_t acc[2][16];
#pragma unroll
  for (int rf = 0; rf < 2; ++rf)
#pragma unroll
    for (int n = 0; n < 16; ++n) acc[rf][n] = (f32x4_t){0.f, 0.f, 0.f, 0.f};

  const char* bbytes = reinterpret_cast<const char*>(Bh);
  const int lane16 = l * 16;

  // 3-deep A register sets (named; indices static under full unroll)
  float4 A0[2][2], A1[2][2], A2[2][2];

  // ---- prologue: batches 0,1,2 (each: 4 gload_lds + 4 float4), fence-pinned ----
#pragma unroll
  for (int j = 0; j < 4; ++j)
    gload16(bbytes + ((wv << 2) + j) * 1024 + lane16,
            (char*)&Bs[0][0] + ((wv << 2) + j) * 1024);
  A0[0][0] = *reinterpret_cast<const float4*>(xrow0 + g * 8);
  A0[0][1] = *reinterpret_cast<const float4*>(xrow0 + g * 8 + 4);
  A0[1][0] = *reinterpret_cast<const float4*>(xrow1 + g * 8);
  A0[1][1] = *reinterpret_cast<const float4*>(xrow1 + g * 8 + 4);
  asm volatile("" ::: "memory");
#pragma unroll
  for (int j = 0; j < 4; ++j)
    gload16(bbytes + 16384 + ((wv << 2) + j) * 1024 + lane16,
            (char*)&Bs[1][0] + ((wv << 2) + j) * 1024);
  A1[0][0] = *reinterpret_cast<const float4*>(xrow0 + 32 + g * 8);
  A1[0][1] = *reinterpret_cast<const float4*>(xrow0 + 32 + g * 8 + 4);
  A1[1][0] = *reinterpret_cast<const float4*>(xrow1 + 32 + g * 8);
  A1[1][1] = *reinterpret_cast<const float4*>(xrow1 + 32 + g * 8 + 4);
  asm volatile("" ::: "memory");
#pragma unroll
  for (int j = 0; j < 4; ++j)
    gload16(bbytes + 32768 + ((wv << 2) + j) * 1024 + lane16,
            (char*)&Bs[2][0] + ((wv << 2) + j) * 1024);
  A2[0][0] = *reinterpret_cast<const float4*>(xrow0 + 64 + g * 8);
  A2[0][1] = *reinterpret_cast<const float4*>(xrow0 + 64 + g * 8 + 4);
  A2[1][0] = *reinterpret_cast<const float4*>(xrow1 + 64 + g * 8);
  A2[1][1] = *reinterpret_cast<const float4*>(xrow1 + 64 + g * 8 + 4);

#pragma unroll
  for (int kc = 0; kc < 16; ++kc) {
    // retire own-wave batch kc: outstanding = {kc,kc+1,kc+2} = 24 ops -> 16
    if (kc <= 13) {
      asm volatile("s_waitcnt vmcnt(16)" ::: "memory");
    } else if (kc == 14) {
      asm volatile("s_waitcnt vmcnt(8)" ::: "memory");
    } else {
      asm volatile("s_waitcnt vmcnt(0)" ::: "memory");
    }
    __builtin_amdgcn_s_barrier();
    asm volatile("" ::: "memory");           // IR fence
    __builtin_amdgcn_sched_barrier(0);       // MIR fence

    // A fragments of batch kc (set kc%3) -- read BEFORE overwrite below
    half8_t ah0, ah1;
    if (kc % 3 == 0)      { ah0 = cvt8(A0[0][0], A0[0][1]); ah1 = cvt8(A0[1][0], A0[1][1]); }
    else if (kc % 3 == 1) { ah0 = cvt8(A1[0][0], A1[0][1]); ah1 = cvt8(A1[1][0], A1[1][1]); }
    else                  { ah0 = cvt8(A2[0][0], A2[0][1]); ah1 = cvt8(A2[1][0], A2[1][1]); }

    // issue batch kc+3 -> Bs[(kc+3)%4] (readers closed at this barrier), A set kc%3
    if (kc <= 12) {
      const char* gb = bbytes + (kc + 3) * 16384;
      char* lb = (char*)&Bs[(kc + 3) % 4][0];
#pragma unroll
      for (int j = 0; j < 4; ++j)
        gload16(gb + ((wv << 2) + j) * 1024 + lane16, lb + ((wv << 2) + j) * 1024);
      const float* xp0 = xrow0 + (kc + 3) * 32 + g * 8;
      const float* xp1 = xrow1 + (kc + 3) * 32 + g * 8;
      if (kc % 3 == 0) {
        A0[0][0] = *reinterpret_cast<const float4*>(xp0);
        A0[0][1] = *reinterpret_cast<const float4*>(xp0 + 4);
        A0[1][0] = *reinterpret_cast<const float4*>(xp1);
        A0[1][1] = *reinterpret_cast<const float4*>(xp1 + 4);
      } else if (kc % 3 == 1) {
        A1[0][0] = *reinterpret_cast<const float4*>(xp0);
        A1[0][1] = *reinterpret_cast<const float4*>(xp0 + 4);
        A1[1][0] = *reinterpret_cast<const float4*>(xp1);
        A1[1][1] = *reinterpret_cast<const float4*>(xp1 + 4);
      } else {
        A2[0][0] = *reinterpret_cast<const float4*>(xp0);
        A2[0][1] = *reinterpret_cast<const float4*>(xp0 + 4);
        A2[1][0] = *reinterpret_cast<const float4*>(xp1);
        A2[1][1] = *reinterpret_cast<const float4*>(xp1 + 4);
      }
    }

    const _Float16* bp = &Bs[kc % 4][0];
    __builtin_amdgcn_s_setprio(1);
#pragma unroll
    for (int n = 0; n < 16; ++n) {
      half8_t bh = *reinterpret_cast<const half8_t*>(&bp[n * 512 + l * 8]);
      acc[0][n] = __builtin_amdgcn_mfma_f32_16x16x32_f16(ah0, bh, acc[0][n], 0, 0, 0);
      acc[1][n] = __builtin_amdgcn_mfma_f32_16x16x32_f16(ah1, bh, acc[1][n], 0, 0, 0);
    }
    __builtin_amdgcn_s_setprio(0);
  }

#pragma unroll
  for (int rf = 0; rf < 2; ++rf) {
    float ssq[4] = {0.f, 0.f, 0.f, 0.f}, dtq[4] = {0.f, 0.f, 0.f, 0.f};
#pragma unroll
    for (int n = 0; n < 16; ++n) {
      float bvn = bm[n * 16 + c];
      float wvn = w2[n * 16 + c];
#pragma unroll
      for (int q = 0; q < 4; ++q) {
        float v = acc[rf][n][q] + bvn;
        v = v > 0.f ? v : 0.f;
        acc[rf][n][q] = v;
        ssq[q] = fmaf(v, v, ssq[q]);
        dtq[q] = fmaf(v, wvn, dtq[q]);
      }
    }
#pragma unroll
    for (int q = 0; q < 4; ++q) {
#pragma unroll
      for (int d = 1; d < 16; d <<= 1) {
        ssq[q] += __shfl_xor(ssq[q], d, 16);
        dtq[q] += __shfl_xor(dtq[q], d, 16);
      }
    }
    float inv[4];
#pragma unroll
    for (int q = 0; q < 4; ++q) {
      float nr = sqrtf(ssq[q]);
      inv[q] = 1.f / fmaxf(nr, 1e-12f);
      int r = row0 + rf * 16 + g * 4 + q;
      if (c == 0 && r < M) wnorm[r] = expf(dtq[q]) * nr;
    }
#pragma unroll
    for (int q = 0; q < 4; ++q) {
      int r = row0 + rf * 16 + g * 4 + q;
      if (r < M) {
#pragma unroll
        for (int n = 0; n < 16; ++n) {
          float v = acc[rf][n][q] * inv[q];
          Yn[(size_t)r * DD + n * 16 + c] = v;
          Y16[(size_t)r * DD + n * 16 + c] = (_Float16)v;
        }
      }
    }
  }
}

// ---- CSR build ----
__global__ void hist_kernel(const int* __restrict__ src, int* __restrict__ deg, int E) {
  int i = blockIdx.x * blockDim.x + threadIdx.x;
  if (i < E) atomicAdd(&deg[src[i]], 1);
}

__global__ __launch_bounds__(256) void scan_part(const int* __restrict__ deg,
                                                 int* __restrict__ bsum, int NP) {
  __shared__ int s[256];
  int t = threadIdx.x, b = blockIdx.x;
  int i0 = (b * 256 + t) * 2;
  int v0 = (i0 < NP) ? deg[i0] : 0;
  int v1 = (i0 + 1 < NP) ? deg[i0 + 1] : 0;
  s[t] = v0 + v1;
  __syncthreads();
  for (int off = 128; off; off >>= 1) {
    if (t < off) s[t] += s[t + off];
    __syncthreads();
  }
  if (t == 0) bsum[b] = s[0];
}

__global__ __launch_bounds__(256) void scan_fin2(const int* __restrict__ deg,
                                                 const int* __restrict__ bsum,
                                                 int* __restrict__ rowptr,
                                                 int* __restrict__ cursor, int NP) {
  __shared__ int s[256];
  __shared__ int base_s;
  int t = threadIdx.x, b = blockIdx.x;
  int v = (t < b) ? bsum[t] : 0;
  s[t] = v;
  __syncthreads();
  for (int off = 128; off; off >>= 1) {
    if (t < off) s[t] += s[t + off];
    __syncthreads();
  }
  if (t == 0) base_s = s[0];
  __syncthreads();
  int base0 = base_s;
  __syncthreads();
  int i0 = (b * 256 + t) * 2;
  int v0 = (i0 < NP) ? deg[i0] : 0;
  int v1 = (i0 + 1 < NP) ? deg[i0 + 1] : 0;
  int local = v0 + v1;
  s[t] = local;
  __syncthreads();
  for (int off = 1; off < 256; off <<= 1) {
    int u = (t >= off) ? s[t - off] : 0;
    __syncthreads();
    s[t] += u;
    __syncthreads();
  }
  int myb = base0 + s[t] - local;
  if (i0 < NP) { rowptr[i0] = myb; cursor[i0] = myb; }
  if (i0 + 1 < NP) { rowptr[i0 + 1] = myb + v0; cursor[i0 + 1] = myb + v0; }
  if (b == gridDim.x - 1 && t == 255) rowptr[NP] = base0 + s[255];
}

__global__ void fill_kernel(const int* __restrict__ src, const int* __restrict__ dst,
                            int* __restrict__ cursor, int* __restrict__ ebuf, int E) {
  int i = blockIdx.x * blockDim.x + threadIdx.x;
  if (i < E) {
    int pos = atomicAdd(&cursor[src[i]], 1);
    ebuf[pos] = dst[i];
  }
}

// ---- per-segment: out = l2norm(sum wnorm[d] * hon16[d]); 16 lanes/node ----
__global__ __launch_bounds__(256) void agg_kernel(const int* __restrict__ rowptr,
                                                  const int* __restrict__ ebuf,
                                                  const float* __restrict__ wnorm,
                                                  const _Float16* __restrict__ hon16,
                                                  float* __restrict__ agg, int NP) {
  long gid = (long)blockIdx.x * blockDim.x + threadIdx.x;
  int wid = (int)(gid >> 6);
  int lane = threadIdx.x & 63;
  int sg = lane >> 4;
  int li = lane & 15;
  int p = wid * 4 + sg;
  if (p >= NP) return;
  int beg = rowptr[p], end = rowptr[p + 1];
  float acc[16];
#pragma unroll
  for (int k = 0; k < 16; ++k) acc[k] = 0.f;
  if (beg < end) {
    int d = ebuf[beg];
    float w = wnorm[d];
    const half8_t* rp = reinterpret_cast<const half8_t*>(&hon16[(size_t)d * DD + li * 16]);
    half8_t v0 = rp[0], v1 = rp[1];
    for (int j = beg + 1; j <= end; ++j) {
      half8_t n0, n1;
      float wn_ = 0.f;
      bool have = (j < end);
      if (have) {
        int dn = ebuf[j];
        wn_ = wnorm[dn];
        const half8_t* np_ = reinterpret_cast<const half8_t*>(&hon16[(size_t)dn * DD + li * 16]);
        n0 = np_[0]; n1 = np_[1];
      }
#pragma unroll
      for (int k = 0; k < 8; ++k) {
        acc[k] = fmaf(w, (float)v0[k], acc[k]);
        acc[8 + k] = fmaf(w, (float)v1[k], acc[8 + k]);
      }
      if (have) { w = wn_; v0 = n0; v1 = n1; }
    }
  }
  float ss = 0.f;
#pragma unroll
  for (int k = 0; k < 16; ++k) ss = fmaf(acc[k], acc[k], ss);
#pragma unroll
  for (int d2 = 8; d2 > 0; d2 >>= 1) ss += __shfl_xor(ss, d2, 16);
  float inv = 1.0f / fmaxf(sqrtf(ss), 1e-12f);
  float* op = &agg[(size_t)p * DD + li * 16];
#pragma unroll
  for (int k = 0; k < 4; ++k) {
    float4 o = {acc[k * 4] * inv, acc[k * 4 + 1] * inv,
                acc[k * 4 + 2] * inv, acc[k * 4 + 3] * inv};
    *reinterpret_cast<float4*>(op + k * 4) = o;
  }
}

extern "C" void kernel_launch(void* const* d_in, const int* in_sizes, int n_in,
                              void* d_out, int out_size, void* d_ws, size_t ws_size,
                              hipStream_t stream) {
  const float* feat_other = (const float*)d_in[1];
  const int* src = (const int*)d_in[2];
  const int* dst = (const int*)d_in[3];
  const float* Wm_o = (const float*)d_in[6];
  const float* bm_o = (const float*)d_in[7];
  const float* W = (const float*)d_in[8];
  const float* a_w = (const float*)d_in[10];

  const int NP = in_sizes[0] / IN_DIM;
  const int NO = in_sizes[1] / IN_DIM;
  const int E = in_sizes[2];

  float* out = (float*)d_out;
  float* agg_out = out;                      // [NP, DD]
  float* ho_out = out + (size_t)NP * DD;     // [NO, DD]

  float* ws = (float*)d_ws;
  float* wnorm = ws;                          // NO
  float* w2 = wnorm + NO;                     // 256
  int* deg = (int*)(w2 + 256);                // NP (memset 0)
  int* rowptr = deg + NP;                     // NP+1
  int* cursor = rowptr + NP + 1;              // NP
  int* bsum = cursor + NP;                    // 256
  int* ebuf = bsum + 256;                     // E
  size_t foff = (size_t)NO + 256 + NP + (NP + 1) + NP + 256 + E;
  foff = (foff + 3) & ~(size_t)3;             // 16B align
  _Float16* Bh = (_Float16*)(ws + foff);      // 131072 halves
  _Float16* Y16 = Bh + (size_t)IN_DIM * DD;   // NO * DD halves

  hipMemsetAsync(deg, 0, (size_t)NP * sizeof(int), stream);

  prep_w2<<<64, 256, 0, stream>>>(W, a_w, w2);
  bconv_kernel<<<(IN_DIM * DD) / 256, 256, 0, stream>>>(Wm_o, Bh);

  map_gemm_mfma<<<(NO + 127) / 128, 256, 0, stream>>>(
      feat_other, Bh, bm_o, w2, ho_out, Y16, wnorm, NO);

  hist_kernel<<<(E + 255) / 256, 256, 0, stream>>>(src, deg, E);
  scan_part<<<256, 256, 0, stream>>>(deg, bsum, NP);
  scan_fin2<<<256, 256, 0, stream>>>(deg, bsum, rowptr, cursor, NP);
  fill_kernel<<<(E + 255) / 256, 256, 0, stream>>>(src, dst, cursor, ebuf, E);

  agg_kernel<<<(NP + 15) / 16, 256, 0, stream>>>(
      rowptr, ebuf, wnorm, Y16, agg_out, NP);
}